// Round 12
// baseline (112.523 us; speedup 1.0000x reference)
//
#include <hip/hip_runtime.h>

#define D 300
#define HDIM 512
#define ROWSB 64          // X rows per block
#define WPB 32            // words per block
#define NKS 19            // K-steps of 16 (304 >= 300)
#define NCHS 24           // chunks per stream: 16 QK (Q/K alternating) + 8 V
#define CH_BYTES 19456    // 32 cols * 304 k * 2 B
#define CH_ELEMS 9728

typedef __attribute__((ext_vector_type(16))) float f32x16;
typedef __attribute__((ext_vector_type(4))) float f32x4;
typedef __attribute__((ext_vector_type(8))) short bf16x8;

__device__ inline unsigned short f2bf(float f) {
  unsigned int u = __float_as_uint(f);
  unsigned int r = (u + 0x7fffu + ((u >> 16) & 1u)) >> 16;
  return (unsigned short)r;
}

__device__ inline void gload_lds16(const void* g, void* l) {
  __builtin_amdgcn_global_load_lds(
      (const __attribute__((address_space(1))) unsigned int*)g,
      (__attribute__((address_space(3))) unsigned int*)l, 16, 0, 0);
}

// 48 chunks = 2 col-half streams x 24. Stream s, local t:
//   t<16:  (t&1 ? Wk : Wq), cols (s*8 + (t>>1))*32 .. +32
//   t>=16: Wv, cols s*256 + (t-16)*32 .. +32
// Chunk layout [ks19][kh2][col32][e8]: lane reads its 32x32x16 B-frag at byte
// hi*512 + lo5*16 + ks*1024 -> wave64 reads 1024 contiguous B (conflict-free,
// R10-verified: 7.9M -> 24K). k >= 300 zero-padded (304 k-extent).
__global__ __launch_bounds__(512) void prep_weights(
    const float* __restrict__ Wq, const float* __restrict__ Wk,
    const float* __restrict__ Wv, unsigned short* __restrict__ wt) {
  int idx = blockIdx.x * 512 + threadIdx.x;
  if (idx >= 48 * CH_ELEMS) return;
  int c = idx / CH_ELEMS, r2 = idx - c * CH_ELEMS;
  int ks = r2 >> 9, r3 = r2 & 511;
  int kh = r3 >> 8, r4 = r3 & 255;
  int col = r4 >> 3, e = r4 & 7;
  int k = ks * 16 + kh * 8 + e;
  int s = c / NCHS, t = c - s * NCHS;
  const float* M; int gcol;
  if (t < 16) { M = (t & 1) ? Wk : Wq; gcol = (s * 8 + (t >> 1)) * 32 + col; }
  else        { M = Wv; gcol = s * 256 + (t - 16) * 32 + col; }
  float v = (k < D) ? M[k * HDIM + gcol] : 0.0f;
  wt[idx] = f2bf(v);
}

// 4-wave blocks (2 row-tiles x 2 col-groups), 64 rows, grid 1024 -> 3-4
// independent blocks/CU. Single-buffered per-group streams; latency hidden by
// cross-block TLP. NOTE: no 2nd __launch_bounds__ arg (R4-R6: forces spill).
__global__ __launch_bounds__(256) void fused_attn(
    const float* __restrict__ charv, const float* __restrict__ wordv,
    const unsigned short* __restrict__ wt,
    const float* __restrict__ bk, const float* __restrict__ bq,
    const float* __restrict__ bv, float* __restrict__ out) {
  extern __shared__ char lds[];
  float* sS  = (float*)(lds + 2 * CH_BYTES);  // [2 grp][32 w][4]
  float* sAt = sS + 256;                      // [32 w][4]

  const int tid   = threadIdx.x;
  const int wid   = tid >> 6;
  const int lane  = tid & 63;
  const int lo5   = lane & 31;
  const int hi    = lane >> 5;
  const int group = wid >> 1;   // col-half
  const int rt    = wid & 1;    // row-tile (rows rt*32..+32)

  auto stage = [&](int t) {
    const char* src = (const char*)wt + (long)(group * NCHS + t) * CH_BYTES
                      + rt * 10240 + lane * 16;
    char* dst = lds + group * CH_BYTES + rt * 10240;
    const int nseg = rt ? 9 : 10;   // 19 segs split 10/9 across the 2 waves
    for (int j = 0; j < nseg; ++j)
      gload_lds16(src + j * 1024, dst + j * 1024);
  };

  // ---- prologue: X -> a[19] regs, stage chunk 0
  bf16x8 a[NKS];
  {
    int row = blockIdx.x * ROWSB + rt * 32 + lo5;
    const float* rp = ((row & 1) ? charv : wordv) + (row >> 1) * D;
#pragma unroll
    for (int ks = 0; ks < NKS; ++ks) {
      int k0 = ks * 16 + hi * 8;
      float4 lo = {0.f, 0.f, 0.f, 0.f}, hif = {0.f, 0.f, 0.f, 0.f};
      if (k0 + 8 <= D) {
        lo  = *(const float4*)(rp + k0);
        hif = *(const float4*)(rp + k0 + 4);
      } else if (k0 < D) {
        lo  = *(const float4*)(rp + k0);
      }
      bf16x8 v;
      v[0] = (short)f2bf(lo.x);  v[1] = (short)f2bf(lo.y);
      v[2] = (short)f2bf(lo.z);  v[3] = (short)f2bf(lo.w);
      v[4] = (short)f2bf(hif.x); v[5] = (short)f2bf(hif.y);
      v[6] = (short)f2bf(hif.z); v[7] = (short)f2bf(hif.w);
      a[ks] = v;
    }
  }
  stage(0);

  float p[32];
#pragma unroll
  for (int t = 0; t < 32; ++t) p[t] = 0.f;

  const int fro = hi * 512 + lo5 * 16;   // B-frag base within a ks-block
  f32x16 accQ;

  // ---- Phase A: 8 (Q,K) chunk pairs per stream, single-buffered
  for (int g = 0; g < 8; ++g) {
    // t = 2g : Q chunk
    asm volatile("s_waitcnt vmcnt(0)" ::: "memory");   // own stage(2g) landed
    __builtin_amdgcn_s_barrier();                      // everyone's landed
    {
      const char* base = lds + group * CH_BYTES + fro;
      float bqv = bq[(group * 8 + g) * 32 + lo5];
#pragma unroll
      for (int r = 0; r < 16; ++r) accQ[r] = bqv;
#pragma unroll
      for (int ks = 0; ks < NKS; ++ks) {
        bf16x8 qb = *(const bf16x8*)(base + ks * 1024);
        accQ = __builtin_amdgcn_mfma_f32_32x32x16_bf16(a[ks], qb, accQ, 0, 0, 0);
      }
    }
    asm volatile("s_waitcnt lgkmcnt(0)" ::: "memory"); // my reads of buf done
    __builtin_amdgcn_s_barrier();                      // all reads done
    stage(2 * g + 1);                                  // overwrite buffer

    // t = 2g+1 : K chunk
    asm volatile("s_waitcnt vmcnt(0)" ::: "memory");
    __builtin_amdgcn_s_barrier();
    {
      const char* base = lds + group * CH_BYTES + fro;
      float bkv = bk[(group * 8 + g) * 32 + lo5];
      f32x16 accK;
#pragma unroll
      for (int r = 0; r < 16; ++r) accK[r] = bkv;
#pragma unroll
      for (int ks = 0; ks < NKS; ++ks) {
        bf16x8 kb = *(const bf16x8*)(base + ks * 1024);
        accK = __builtin_amdgcn_mfma_f32_32x32x16_bf16(a[ks], kb, accK, 0, 0, 0);
      }
      // lane-local score partials (same lane holds Q and K of same word/col)
#pragma unroll
      for (int tt = 0; tt < 8; ++tt)
#pragma unroll
        for (int i = 0; i < 2; ++i)
#pragma unroll
          for (int j = 0; j < 2; ++j)
            p[tt * 4 + i * 2 + j] += accQ[2 * tt + i] * accK[2 * tt + j];
    }
    asm volatile("s_waitcnt lgkmcnt(0)" ::: "memory");
    __builtin_amdgcn_s_barrier();
    stage(2 * g + 2);   // g=7 -> stage(16) = first V chunk
  }

  // ---- scores: shfl-reduce over 32 col-lanes, combine col-groups, softmax
#pragma unroll
  for (int t = 0; t < 32; ++t) {
    float v = p[t];
    v += __shfl_xor(v, 1);
    v += __shfl_xor(v, 2);
    v += __shfl_xor(v, 4);
    v += __shfl_xor(v, 8);
    v += __shfl_xor(v, 16);
    p[t] = v;
  }
  if (lo5 == 0) {
#pragma unroll
    for (int tt = 0; tt < 8; ++tt) {
      int w = rt * 16 + (tt >> 1) * 4 + (tt & 1) + hi * 2;
#pragma unroll
      for (int q = 0; q < 4; ++q) sS[group * 128 + w * 4 + q] = p[tt * 4 + q];
    }
  }
  asm volatile("s_waitcnt lgkmcnt(0)" ::: "memory");
  __builtin_amdgcn_s_barrier();
  if (tid < 32) {
    const float sc = 0.044194173824159216f;  // 1/sqrt(512)
    float s[4];
#pragma unroll
    for (int t = 0; t < 4; ++t) s[t] = (sS[tid * 4 + t] + sS[128 + tid * 4 + t]) * sc;
#pragma unroll
    for (int i = 0; i < 2; ++i) {
      float m  = fmaxf(s[i * 2], s[i * 2 + 1]);
      float e0 = expf(s[i * 2] - m), e1 = expf(s[i * 2 + 1] - m);
      float inv = 1.0f / (e0 + e1);
      sAt[tid * 4 + i * 2]     = e0 * inv;
      sAt[tid * 4 + i * 2 + 1] = e1 * inv;
    }
  }
  asm volatile("s_waitcnt lgkmcnt(0)" ::: "memory");
  __builtin_amdgcn_s_barrier();

  f32x4 at[8];
#pragma unroll
  for (int tt = 0; tt < 8; ++tt) {
    int w = rt * 16 + (tt >> 1) * 4 + (tt & 1) + hi * 2;
    at[tt] = *(const f32x4*)(sAt + w * 4);
  }

  // ---- Phase B: 8 V chunks per stream + attention combine
  for (int t = 16; t < NCHS; ++t) {
    asm volatile("s_waitcnt vmcnt(0)" ::: "memory");   // own stage(t) landed
    __builtin_amdgcn_s_barrier();
    const char* base = lds + group * CH_BYTES + fro;
    const int g = t - 16;
    float bvv = bv[(group * 8 + g) * 32 + lo5];
    f32x16 accV;
#pragma unroll
    for (int r = 0; r < 16; ++r) accV[r] = bvv;
#pragma unroll
    for (int ks = 0; ks < NKS; ++ks) {
      bf16x8 vb = *(const bf16x8*)(base + ks * 1024);
      accV = __builtin_amdgcn_mfma_f32_32x32x16_bf16(a[ks], vb, accV, 0, 0, 0);
    }
    int h = group * 256 + g * 32 + lo5;
#pragma unroll
    for (int tt = 0; tt < 8; ++tt) {
      int w = rt * 16 + (tt >> 1) * 4 + (tt & 1) + hi * 2;
      long gw = (long)(blockIdx.x * WPB + w);
      float v0 = accV[2 * tt], v1 = accV[2 * tt + 1];
      out[gw * 1024 + h]       = at[tt][0] * v0 + at[tt][1] * v1;
      out[gw * 1024 + 512 + h] = at[tt][2] * v0 + at[tt][3] * v1;
    }
    if (t + 1 < NCHS) {
      asm volatile("s_waitcnt lgkmcnt(0)" ::: "memory");
      __builtin_amdgcn_s_barrier();
      stage(t + 1);
    }
  }
}

extern "C" void kernel_launch(void* const* d_in, const int* in_sizes, int n_in,
                              void* d_out, int out_size, void* d_ws, size_t ws_size,
                              hipStream_t stream) {
  const float* charv = (const float*)d_in[0];
  const float* wordv = (const float*)d_in[1];
  const float* Wk = (const float*)d_in[2];
  const float* bk = (const float*)d_in[3];
  const float* Wq = (const float*)d_in[4];
  const float* bq = (const float*)d_in[5];
  const float* Wv = (const float*)d_in[6];
  const float* bv = (const float*)d_in[7];
  float* out = (float*)d_out;
  unsigned short* wt = (unsigned short*)d_ws;  // 48*9728*2 = 933,888 B

  prep_weights<<<(48 * CH_ELEMS + 511) / 512, 512, 0, stream>>>(Wq, Wk, Wv, wt);

  const int lds_bytes = 2 * CH_BYTES + 256 * 4 + 128 * 4;  // 40,448 B -> 4 blocks/CU
  fused_attn<<<65536 / ROWSB, 256, lds_bytes, stream>>>(charv, wordv, wt, bk, bq, bv, out);
}